// Round 18
// baseline (298.751 us; speedup 1.0000x reference)
//
#include <hip/hip_runtime.h>

#define CH 128          // C_IN == C_OUT == 128
#define SUMS_BLOCK 512
#define CHUNK_E 4096    // records per chunk = private recsTmp window
#define RPT 16          // records per thread in passA (CHUNK_E / 256)
#define BUCKET_BITS 10  // 1024 keys per bucket
#define BKEYS (1 << BUCKET_BITS)
#define NBMAX 512       // max buckets (LDS arrays padded to this)
#define STAG_CAP 18432  // passB LDS out-buffer capacity

__device__ inline ushort f2bf(float f) {          // RNE f32 -> bf16
    unsigned b = __float_as_uint(f);
    return (ushort)((b + 0x7FFF + ((b >> 16) & 1)) >> 16);
}
__device__ inline float bf2f(ushort u) {
    return __uint_as_float((unsigned)u << 16);
}

// ---------- W -> bf16 conversion ----------
__global__ void conv_w_kernel(const float* __restrict__ W,
                              ushort* __restrict__ Wb) {
    int i = blockIdx.x * blockDim.x + threadIdx.x;
    if (i < CH * CH) Wb[i] = f2bf(W[i]);
}

// ---------- pass A: single-read, register-held chunk sort (R16 version) ---
// Triple key space: Phi_inv i -> idxA[i]; Phi -> n+idxB[e]; F -> 2n+idxC[e].
// recsTmp record (8 B): x = c | (key&1023)<<17  (c < 2^17), y = f32 val bits.
__global__ __launch_bounds__(256) void passA_sort(const int* __restrict__ idxA,
                                                  const float* __restrict__ valA,
                                                  const int* __restrict__ idxB,
                                                  const float* __restrict__ valB,
                                                  const int* __restrict__ idxC,
                                                  const float* __restrict__ valC,
                                                  const float* __restrict__ theta,
                                                  int nnz, int n, int nb,
                                                  int* __restrict__ locA,
                                                  int2* __restrict__ recsTmp) {
    __shared__ int hist[NBMAX];
    __shared__ int sc[NBMAX];
    __shared__ int cur[NBMAX];
    int t = threadIdx.x;
    hist[t] = 0; hist[t + 256] = 0;
    __syncthreads();

    int base = blockIdx.x * CHUNK_E;
    int end = min(base + CHUNK_E, 3 * nnz);
    int csize = end - base;
    int rbeg = base + t * RPT;

    int px[RPT];    // packed x (c | keylow<<17)
    int pv[RPT];    // value bits (f32)
    short pb[RPT];  // bucket id

    int nvalid = 0;
    if (rbeg + RPT <= nnz) {
        #pragma unroll
        for (int r4 = 0; r4 < RPT / 4; ++r4) {
            int4 k4 = *reinterpret_cast<const int4*>(&idxA[rbeg + r4 * 4]);
            int4 c4 = *reinterpret_cast<const int4*>(&idxA[nnz + rbeg + r4 * 4]);
            float4 v4 = *reinterpret_cast<const float4*>(&valA[rbeg + r4 * 4]);
            int kk[4] = {k4.x, k4.y, k4.z, k4.w};
            int cc[4] = {c4.x, c4.y, c4.z, c4.w};
            float vv[4] = {v4.x, v4.y, v4.z, v4.w};
            #pragma unroll
            for (int u = 0; u < 4; ++u) {
                int r = r4 * 4 + u;
                px[r] = cc[u] | ((kk[u] & (BKEYS - 1)) << 17);
                pv[r] = __float_as_int(vv[u]);
                pb[r] = (short)(kk[u] >> BUCKET_BITS);
                atomicAdd(&hist[pb[r]], 1);
            }
        }
        nvalid = RPT;
    } else if (rbeg >= nnz && rbeg + RPT <= 2 * nnz) {
        int e0 = rbeg - nnz;
        #pragma unroll
        for (int r4 = 0; r4 < RPT / 4; ++r4) {
            int4 k4 = *reinterpret_cast<const int4*>(&idxB[e0 + r4 * 4]);
            int4 c4 = *reinterpret_cast<const int4*>(&idxB[nnz + e0 + r4 * 4]);
            float4 v4 = *reinterpret_cast<const float4*>(&valB[e0 + r4 * 4]);
            int kk[4] = {k4.x, k4.y, k4.z, k4.w};
            int cc[4] = {c4.x, c4.y, c4.z, c4.w};
            float vv[4] = {v4.x, v4.y, v4.z, v4.w};
            #pragma unroll
            for (int u = 0; u < 4; ++u) {
                int r = r4 * 4 + u;
                int key = n + kk[u];
                px[r] = cc[u] | ((key & (BKEYS - 1)) << 17);
                pv[r] = __float_as_int(vv[u] * theta[cc[u]]);
                pb[r] = (short)(key >> BUCKET_BITS);
                atomicAdd(&hist[pb[r]], 1);
            }
        }
        nvalid = RPT;
    } else if (rbeg >= 2 * nnz && rbeg + RPT <= 3 * nnz) {
        int e0 = rbeg - 2 * nnz;
        #pragma unroll
        for (int r4 = 0; r4 < RPT / 4; ++r4) {
            int4 k4 = *reinterpret_cast<const int4*>(&idxC[e0 + r4 * 4]);
            int4 c4 = *reinterpret_cast<const int4*>(&idxC[nnz + e0 + r4 * 4]);
            float4 v4 = *reinterpret_cast<const float4*>(&valC[e0 + r4 * 4]);
            int kk[4] = {k4.x, k4.y, k4.z, k4.w};
            int cc[4] = {c4.x, c4.y, c4.z, c4.w};
            float vv[4] = {v4.x, v4.y, v4.z, v4.w};
            #pragma unroll
            for (int u = 0; u < 4; ++u) {
                int r = r4 * 4 + u;
                int key = 2 * n + kk[u];
                px[r] = cc[u] | ((key & (BKEYS - 1)) << 17);
                pv[r] = __float_as_int(vv[u]);
                pb[r] = (short)(key >> BUCKET_BITS);
                atomicAdd(&hist[pb[r]], 1);
            }
        }
        nvalid = RPT;
    } else {
        #pragma unroll
        for (int r = 0; r < RPT; ++r) {
            int i = rbeg + r;
            if (i >= end) break;
            int key, c;
            float v;
            if (i < nnz) {
                key = idxA[i];
                c = idxA[nnz + i];
                v = valA[i];
            } else if (i < 2 * nnz) {
                int e = i - nnz;
                key = n + idxB[e];
                c = idxB[nnz + e];
                v = valB[e] * theta[c];
            } else {
                int e = i - 2 * nnz;
                key = 2 * n + idxC[e];
                c = idxC[nnz + e];
                v = valC[e];
            }
            px[r] = c | ((key & (BKEYS - 1)) << 17);
            pv[r] = __float_as_int(v);
            pb[r] = (short)(key >> BUCKET_BITS);
            atomicAdd(&hist[pb[r]], 1);
            ++nvalid;
        }
    }
    __syncthreads();

    sc[t] = hist[t]; sc[t + 256] = hist[t + 256];
    __syncthreads();
    for (int off = 1; off < NBMAX; off <<= 1) {
        int a = (t >= off) ? sc[t - off] : 0;
        int b2 = (t + 256 >= off) ? sc[t + 256 - off] : 0;
        __syncthreads();
        sc[t] += a; sc[t + 256] += b2;
        __syncthreads();
    }
    cur[t] = sc[t] - hist[t];
    cur[t + 256] = sc[t + 256] - hist[t + 256];
    __syncthreads();

    for (int b = t; b <= nb; b += 256)
        locA[(size_t)blockIdx.x * (nb + 1) + b] = (b < nb) ? (sc[b] - hist[b]) : csize;

    #pragma unroll
    for (int r = 0; r < RPT; ++r) {
        if (r < nvalid) {
            int pos = atomicAdd(&cur[pb[r]], 1);
            recsTmp[(size_t)base + pos] = make_int2(px[r], pv[r]);
        }
    }
}

// ---------- bucket totals ----------
__global__ __launch_bounds__(256) void bucket_totals(const int* __restrict__ locA,
                                                     int nchA, int nb,
                                                     int* __restrict__ tot) {
    __shared__ int red[256];
    int b = blockIdx.x;
    int t = threadIdx.x;
    int s = 0;
    for (int ch = t; ch < nchA; ch += 256) {
        const int* lc = &locA[(size_t)ch * (nb + 1)];
        s += lc[b + 1] - lc[b];
    }
    red[t] = s;
    __syncthreads();
    for (int off = 128; off > 0; off >>= 1) {
        if (t < off) red[t] += red[t + off];
        __syncthreads();
    }
    if (t == 0) tot[b] = red[0];
}

__global__ void scan_sums_kernel(int* __restrict__ chunk_sums, int nchunks) {
    __shared__ int tmp[SUMS_BLOCK];
    __shared__ int carry_s;
    int tid = threadIdx.x;
    if (tid == 0) carry_s = 0;
    __syncthreads();
    for (int base = 0; base < nchunks; base += SUMS_BLOCK) {
        int i = base + tid;
        int v = (i < nchunks) ? chunk_sums[i] : 0;
        tmp[tid] = v;
        __syncthreads();
        for (int off = 1; off < SUMS_BLOCK; off <<= 1) {
            int y = (tid >= off) ? tmp[tid - off] : 0;
            __syncthreads();
            tmp[tid] += y;
            __syncthreads();
        }
        int c = carry_s;
        if (i < nchunks) chunk_sums[i] = tmp[tid] - v + c;   // exclusive
        int total = tmp[SUMS_BLOCK - 1];
        __syncthreads();
        if (tid == 0) carry_s = c + total;
        __syncthreads();
    }
}

// ---------- pass B v4: key-sort + FUSED F@W compute ----------------------
// For Phi keys (< 2n): as before — scatter into LDS out-buffer, linear
// coalesced flush to recs. For F keys (>= 2n): records stay in LDS; each
// 16-lane group computes filtered[row] = sum val * W[col] directly (W staged
// in 32 KB LDS) and stores packed bf16 — the entire F pull kernel vanishes.
// rec = (c << 15) | (bf16(v) & 0x7FFF)  -- all values positive.
__global__ __launch_bounds__(1024) void passB_kernel(const int2* __restrict__ recsTmp,
                                                     const int* __restrict__ locA,
                                                     const int* __restrict__ bsArr,
                                                     const uint4* __restrict__ w4,
                                                     ushort* __restrict__ filt_b,
                                                     int nchA, int nb, int n, int n3,
                                                     int* __restrict__ start_g,
                                                     int* __restrict__ counts_g,
                                                     unsigned* __restrict__ recs) {
    __shared__ int hist[BKEYS];          // 4 KB
    __shared__ int scan[BKEYS];          // 4 KB
    __shared__ unsigned outb[STAG_CAP];  // 72 KB
    __shared__ uint4 Wlds[CH * 16];      // 32 KB (bf16 W, 8 ch per uint4)
    int b = blockIdx.x;
    int t = threadIdx.x;
    int wave = t >> 6, lane = t & 63;
    int grp = lane >> 4, gl = lane & 15;
    int bs = bsArr[b];
    int keyBase = b << BUCKET_BITS;
    int k2 = 2 * n - keyBase;            // local idx where F range starts
    bool hasF = (k2 < BKEYS);
    hist[t] = 0;
    if (hasF)
        for (int i = t; i < CH * 16; i += 1024) Wlds[i] = w4[i];
    __syncthreads();

    // phase 1: key histogram
    for (int ch = wave * 4 + grp; ch < nchA; ch += 64) {
        const int* lc = &locA[(size_t)ch * (nb + 1)];
        int ls = lc[b], le = lc[b + 1];
        size_t cb = (size_t)ch * CHUNK_E;
        for (int k = ls + gl; k < le; k += 16)
            atomicAdd(&hist[(recsTmp[cb + k].x >> 17) & (BKEYS - 1)], 1);
    }
    __syncthreads();

    // phase 2: scan 1024 keys; CSR metadata
    int v = hist[t];
    scan[t] = v;
    __syncthreads();
    for (int off = 1; off < BKEYS; off <<= 1) {
        int y = (t >= off) ? scan[t - off] : 0;
        __syncthreads();
        scan[t] += y;
        __syncthreads();
    }
    int excl = scan[t] - v;
    int key = keyBase + t;
    if (key < n3) {
        start_g[key] = bs + excl;
        counts_g[key] = v;
    }
    int totalB = scan[BKEYS - 1];
    hist[t] = excl;                      // reuse as cursor
    __syncthreads();

    // records of keys < 2n form the prefix [0, flushEnd) of this bucket
    int flushEnd;
    if (k2 >= BKEYS)      flushEnd = totalB;               // all Phi
    else if (k2 <= 0)     flushEnd = 0;                    // all F
    else                  flushEnd = scan[k2 - 1];         // mixed bucket

    #define FACC(wv, vf) \
        a0 = fmaf(vf, __uint_as_float((wv).x << 16), a0);           \
        a1 = fmaf(vf, __uint_as_float((wv).x & 0xFFFF0000u), a1);   \
        a2 = fmaf(vf, __uint_as_float((wv).y << 16), a2);           \
        a3 = fmaf(vf, __uint_as_float((wv).y & 0xFFFF0000u), a3);   \
        a4 = fmaf(vf, __uint_as_float((wv).z << 16), a4);           \
        a5 = fmaf(vf, __uint_as_float((wv).z & 0xFFFF0000u), a5);   \
        a6 = fmaf(vf, __uint_as_float((wv).w << 16), a6);           \
        a7 = fmaf(vf, __uint_as_float((wv).w & 0xFFFF0000u), a7);

    if (totalB <= STAG_CAP) {
        // phase 3: scatter packed 4B records into LDS out-buffer
        for (int ch = wave * 4 + grp; ch < nchA; ch += 64) {
            const int* lc = &locA[(size_t)ch * (nb + 1)];
            int ls = lc[b], le = lc[b + 1];
            size_t cb = (size_t)ch * CHUNK_E;
            for (int k = ls + gl; k < le; k += 16) {
                int2 r = recsTmp[cb + k];
                int kk = (r.x >> 17) & (BKEYS - 1);
                int pos = atomicAdd(&hist[kk], 1);
                unsigned c = (unsigned)(r.x & 0x1FFFF);
                unsigned bv = (unsigned)f2bf(__int_as_float(r.y)) & 0x7FFFu;
                outb[pos] = (c << 15) | bv;
            }
        }
        __syncthreads();
        // phase 4: linear coalesced flush of the Phi prefix only
        for (int k = t; k < flushEnd; k += 1024)
            recs[(size_t)bs + k] = outb[k];
        // phase 5: fused F@W from LDS records + LDS W
        if (hasF) {
            int grp64 = t >> 4, l16 = t & 15;
            for (int idx = grp64; idx < BKEYS; idx += 64) {
                int ky = keyBase + idx;
                if (ky < 2 * n || ky >= n3) continue;
                int rs = idx ? scan[idx - 1] : 0;
                int re = scan[idx];
                float a0 = 0, a1 = 0, a2 = 0, a3 = 0, a4 = 0, a5 = 0, a6 = 0, a7 = 0;
                for (int j = rs; j < re; ++j) {
                    unsigned rec = outb[j];
                    float vf = __uint_as_float((rec & 0x7FFFu) << 16);
                    uint4 wv = Wlds[(rec >> 15) * 16 + l16];
                    FACC(wv, vf)
                }
                uint4 o;
                o.x = (unsigned)f2bf(a0) | ((unsigned)f2bf(a1) << 16);
                o.y = (unsigned)f2bf(a2) | ((unsigned)f2bf(a3) << 16);
                o.z = (unsigned)f2bf(a4) | ((unsigned)f2bf(a5) << 16);
                o.w = (unsigned)f2bf(a6) | ((unsigned)f2bf(a7) << 16);
                reinterpret_cast<uint4*>(filt_b)[(size_t)(ky - 2 * n) * 16 + l16] = o;
            }
        }
    } else {
        // fallback (statistically unreachable): direct global scatter of ALL
        // records, then F-compute reading from global recs.
        for (int ch = wave * 4 + grp; ch < nchA; ch += 64) {
            const int* lc = &locA[(size_t)ch * (nb + 1)];
            int ls = lc[b], le = lc[b + 1];
            size_t cb = (size_t)ch * CHUNK_E;
            for (int k = ls + gl; k < le; k += 16) {
                int2 r = recsTmp[cb + k];
                int kk = (r.x >> 17) & (BKEYS - 1);
                int pos = atomicAdd(&hist[kk], 1);
                unsigned c = (unsigned)(r.x & 0x1FFFF);
                unsigned bv = (unsigned)f2bf(__int_as_float(r.y)) & 0x7FFFu;
                recs[(size_t)bs + pos] = (c << 15) | bv;
            }
        }
        __syncthreads();
        if (hasF) {
            int grp64 = t >> 4, l16 = t & 15;
            for (int idx = grp64; idx < BKEYS; idx += 64) {
                int ky = keyBase + idx;
                if (ky < 2 * n || ky >= n3) continue;
                int rs = idx ? scan[idx - 1] : 0;
                int re = scan[idx];
                float a0 = 0, a1 = 0, a2 = 0, a3 = 0, a4 = 0, a5 = 0, a6 = 0, a7 = 0;
                for (int j = rs; j < re; ++j) {
                    unsigned rec = recs[(size_t)bs + j];
                    float vf = __uint_as_float((rec & 0x7FFFu) << 16);
                    uint4 wv = Wlds[(rec >> 15) * 16 + l16];
                    FACC(wv, vf)
                }
                uint4 o;
                o.x = (unsigned)f2bf(a0) | ((unsigned)f2bf(a1) << 16);
                o.y = (unsigned)f2bf(a2) | ((unsigned)f2bf(a3) << 16);
                o.z = (unsigned)f2bf(a4) | ((unsigned)f2bf(a5) << 16);
                o.w = (unsigned)f2bf(a6) | ((unsigned)f2bf(a7) << 16);
                reinterpret_cast<uint4*>(filt_b)[(size_t)(ky - 2 * n) * 16 + l16] = o;
            }
        }
    }
    #undef FACC
}

// ---------- Pull SpMM (R16 version): 32 lanes/row, shfl broadcast ---------
__global__ __launch_bounds__(256) void pull_spmm_bf16(
        const unsigned* __restrict__ recs,
        const int* __restrict__ start,
        const int* __restrict__ counts,
        const ushort* __restrict__ dense,   // bf16 rows of 128
        ushort* __restrict__ outb,          // bf16 out (or null)
        float* __restrict__ outf,           // f32 out (or null)
        int n, int do_relu) {
    int grp32 = threadIdx.x >> 5;           // 8 row-groups per block
    int lane = threadIdx.x & 31;
    int row = blockIdx.x * 8 + grp32;
    if (row >= n) return;
    int s = start[row];
    int cnt = counts[row];
    const ushort4* dp = reinterpret_cast<const ushort4*>(dense);  // 32 per row
    float a0 = 0.0f, a1 = 0.0f, a2 = 0.0f, a3 = 0.0f;

    for (int jb = 0; jb < cnt; jb += 32) {
        int nbatch = min(32, cnt - jb);
        unsigned myrec = (lane < nbatch) ? recs[s + jb + lane] : 0u;
        int j = 0;
        for (; j + 4 <= nbatch; j += 4) {
            unsigned r0 = __shfl(myrec, j + 0, 32);
            unsigned r1 = __shfl(myrec, j + 1, 32);
            unsigned r2 = __shfl(myrec, j + 2, 32);
            unsigned r3 = __shfl(myrec, j + 3, 32);
            ushort4 d0 = dp[(size_t)(r0 >> 15) * 32 + lane];
            ushort4 d1 = dp[(size_t)(r1 >> 15) * 32 + lane];
            ushort4 d2 = dp[(size_t)(r2 >> 15) * 32 + lane];
            ushort4 d3 = dp[(size_t)(r3 >> 15) * 32 + lane];
            float v0 = __uint_as_float((r0 & 0x7FFFu) << 16);
            float v1 = __uint_as_float((r1 & 0x7FFFu) << 16);
            float v2 = __uint_as_float((r2 & 0x7FFFu) << 16);
            float v3 = __uint_as_float((r3 & 0x7FFFu) << 16);
            a0 = fmaf(v0, bf2f(d0.x), a0); a1 = fmaf(v0, bf2f(d0.y), a1);
            a2 = fmaf(v0, bf2f(d0.z), a2); a3 = fmaf(v0, bf2f(d0.w), a3);
            a0 = fmaf(v1, bf2f(d1.x), a0); a1 = fmaf(v1, bf2f(d1.y), a1);
            a2 = fmaf(v1, bf2f(d1.z), a2); a3 = fmaf(v1, bf2f(d1.w), a3);
            a0 = fmaf(v2, bf2f(d2.x), a0); a1 = fmaf(v2, bf2f(d2.y), a1);
            a2 = fmaf(v2, bf2f(d2.z), a2); a3 = fmaf(v2, bf2f(d2.w), a3);
            a0 = fmaf(v3, bf2f(d3.x), a0); a1 = fmaf(v3, bf2f(d3.y), a1);
            a2 = fmaf(v3, bf2f(d3.z), a2); a3 = fmaf(v3, bf2f(d3.w), a3);
        }
        for (; j < nbatch; ++j) {
            unsigned r0 = __shfl(myrec, j, 32);
            ushort4 d0 = dp[(size_t)(r0 >> 15) * 32 + lane];
            float v0 = __uint_as_float((r0 & 0x7FFFu) << 16);
            a0 = fmaf(v0, bf2f(d0.x), a0); a1 = fmaf(v0, bf2f(d0.y), a1);
            a2 = fmaf(v0, bf2f(d0.z), a2); a3 = fmaf(v0, bf2f(d0.w), a3);
        }
    }
    if (do_relu) {
        a0 = fmaxf(a0, 0.0f); a1 = fmaxf(a1, 0.0f);
        a2 = fmaxf(a2, 0.0f); a3 = fmaxf(a3, 0.0f);
    }
    if (outb) {
        ushort4 o = {f2bf(a0), f2bf(a1), f2bf(a2), f2bf(a3)};
        reinterpret_cast<ushort4*>(outb)[(size_t)row * 32 + lane] = o;
    } else {
        float4 o = {a0, a1, a2, a3};
        *reinterpret_cast<float4*>(&outf[(size_t)row * CH + lane * 4]) = o;
    }
}

// ---------- host-side orchestration ----------

extern "C" void kernel_launch(void* const* d_in, const int* in_sizes, int n_in,
                              void* d_out, int out_size, void* d_ws, size_t ws_size,
                              hipStream_t stream) {
    const int*   phi_idx  = (const int*)d_in[0];
    const float* phi_val  = (const float*)d_in[1];
    const int*   phii_idx = (const int*)d_in[2];
    const float* phii_val = (const float*)d_in[3];
    const int*   f_idx    = (const int*)d_in[4];
    const float* f_val    = (const float*)d_in[5];
    const float* W        = (const float*)d_in[6];
    const float* theta    = (const float*)d_in[7];

    const int nnz = in_sizes[1];            // 1,600,000
    const int n   = in_sizes[7];            // 100,000
    const int n3  = 3 * n;                  // triple key space
    const int total = 3 * nnz;              // 4.8M records

    const int nb   = (n3 + BKEYS - 1) >> BUCKET_BITS;               // 293 (<=511)
    const int nchA = (total + CHUNK_E - 1) / CHUNK_E;               // 1172

    float* out = (float*)d_out;

    // workspace (~87 MB). region0 (38.4 MB) holds recsTmp during the build
    // and is reused as z_b after passB. filt_b is a SEPARATE buffer because
    // passB writes it while still reading recsTmp.
    char* ws = (char*)d_ws;
    char* region0   = ws;
    int2* recsTmp   = (int2*)region0;                      // 38.4 MB (build)
    ushort* z_b     = (ushort*)region0;                    // 25.6 MB (after)
    ws += (size_t)total * sizeof(int2);
    unsigned* recs  = (unsigned*)ws;        ws += (size_t)total * sizeof(unsigned);
    int* counts     = (int*)ws;             ws += (size_t)n3 * sizeof(int);
    int* start      = (int*)ws;             ws += (size_t)n3 * sizeof(int);
    int* locA       = (int*)ws;             ws += (size_t)nchA * (nb + 1) * sizeof(int);
    int* tot        = (int*)ws;             ws += 4096;
    ushort* w_b     = (ushort*)ws;          ws += CH * CH * sizeof(ushort);
    ushort* filt_b  = (ushort*)ws;          ws += (size_t)n * CH * sizeof(ushort);

    const int row_blocks = (n + 7) / 8;     // 8 rows per 256-thread block

    // --- W -> bf16 (needed by passB's fused F@W) ---
    conv_w_kernel<<<(CH * CH + 255) / 256, 256, 0, stream>>>(W, w_b);

    // --- radix CSR build + fused F@W ---
    passA_sort<<<nchA, 256, 0, stream>>>(phii_idx, phii_val, phi_idx, phi_val,
                                         f_idx, f_val, theta,
                                         nnz, n, nb, locA, recsTmp);
    bucket_totals<<<nb, 256, 0, stream>>>(locA, nchA, nb, tot);
    scan_sums_kernel<<<1, SUMS_BLOCK, 0, stream>>>(tot, nb);
    passB_kernel<<<nb, 1024, 0, stream>>>(recsTmp, locA, tot,
                                          (const uint4*)w_b, filt_b,
                                          nchA, nb, n, n3,
                                          start, counts, recs);

    // 2) z = Phi_inv @ filtered (keys [0,n); z_b overwrites dead recsTmp)
    pull_spmm_bf16<<<row_blocks, 256, 0, stream>>>(
        recs, start, counts, filt_b, z_b, nullptr, n, 0);

    // 3) out = relu(Phi @ (theta .* z))  (keys [n,2n); theta pre-folded)
    pull_spmm_bf16<<<row_blocks, 256, 0, stream>>>(
        recs, start + n, counts + n, z_b, nullptr, out, n, 1);
}

// Round 19
// 254.364 us; speedup vs baseline: 1.1745x; 1.1745x over previous
//
#include <hip/hip_runtime.h>

#define CH 128          // C_IN == C_OUT == 128
#define SUMS_BLOCK 512
#define CHUNK_E 4096    // records per chunk = private recsTmp window
#define RPT 16          // records per thread in passA (CHUNK_E / 256)
#define BUCKET_BITS 10  // 1024 keys per bucket
#define BKEYS (1 << BUCKET_BITS)
#define NBMAX 512       // max buckets (LDS arrays padded to this)
#define STAG_CAP 18432  // passB LDS out-buffer capacity

__device__ inline ushort f2bf(float f) {          // RNE f32 -> bf16
    unsigned b = __float_as_uint(f);
    return (ushort)((b + 0x7FFF + ((b >> 16) & 1)) >> 16);
}
__device__ inline float bf2f(ushort u) {
    return __uint_as_float((unsigned)u << 16);
}

// ---------- W -> bf16 conversion ----------
__global__ void conv_w_kernel(const float* __restrict__ W,
                              ushort* __restrict__ Wb) {
    int i = blockIdx.x * blockDim.x + threadIdx.x;
    if (i < CH * CH) Wb[i] = f2bf(W[i]);
}

// ---------- pass A v5: register-held sort, per-wave hist/cursor replication
// Triple key space: Phi_inv i -> idxA[i]; Phi -> n+idxB[e]; F -> 2n+idxC[e].
// recsTmp record (8 B): x = c | (key&1023)<<17  (c < 2^17), y = f32 val bits.
__global__ __launch_bounds__(256) void passA_sort(const int* __restrict__ idxA,
                                                  const float* __restrict__ valA,
                                                  const int* __restrict__ idxB,
                                                  const float* __restrict__ valB,
                                                  const int* __restrict__ idxC,
                                                  const float* __restrict__ valC,
                                                  const float* __restrict__ theta,
                                                  int nnz, int n, int nb,
                                                  int* __restrict__ locA,
                                                  int2* __restrict__ recsTmp) {
    __shared__ int hist4[4][NBMAX];   // per-wave histograms (8 KB)
    __shared__ int sc[NBMAX];         // inclusive scan of combined hist (2 KB)
    __shared__ int wcur[4][NBMAX];    // per-wave scatter cursors (8 KB)
    int t = threadIdx.x;
    int wv = t >> 6;                  // wave id 0..3
    for (int i = t; i < 4 * NBMAX; i += 256) (&hist4[0][0])[i] = 0;
    __syncthreads();

    int base = blockIdx.x * CHUNK_E;
    int end = min(base + CHUNK_E, 3 * nnz);
    int csize = end - base;
    int rbeg = base + t * RPT;

    int px[RPT];    // packed x (c | keylow<<17)
    int pv[RPT];    // value bits (f32)
    short pb[RPT];  // bucket id

    int nvalid = 0;
    if (rbeg + RPT <= nnz) {
        #pragma unroll
        for (int r4 = 0; r4 < RPT / 4; ++r4) {
            int4 k4 = *reinterpret_cast<const int4*>(&idxA[rbeg + r4 * 4]);
            int4 c4 = *reinterpret_cast<const int4*>(&idxA[nnz + rbeg + r4 * 4]);
            float4 v4 = *reinterpret_cast<const float4*>(&valA[rbeg + r4 * 4]);
            int kk[4] = {k4.x, k4.y, k4.z, k4.w};
            int cc[4] = {c4.x, c4.y, c4.z, c4.w};
            float vv[4] = {v4.x, v4.y, v4.z, v4.w};
            #pragma unroll
            for (int u = 0; u < 4; ++u) {
                int r = r4 * 4 + u;
                px[r] = cc[u] | ((kk[u] & (BKEYS - 1)) << 17);
                pv[r] = __float_as_int(vv[u]);
                pb[r] = (short)(kk[u] >> BUCKET_BITS);
                atomicAdd(&hist4[wv][pb[r]], 1);
            }
        }
        nvalid = RPT;
    } else if (rbeg >= nnz && rbeg + RPT <= 2 * nnz) {
        int e0 = rbeg - nnz;
        #pragma unroll
        for (int r4 = 0; r4 < RPT / 4; ++r4) {
            int4 k4 = *reinterpret_cast<const int4*>(&idxB[e0 + r4 * 4]);
            int4 c4 = *reinterpret_cast<const int4*>(&idxB[nnz + e0 + r4 * 4]);
            float4 v4 = *reinterpret_cast<const float4*>(&valB[e0 + r4 * 4]);
            int kk[4] = {k4.x, k4.y, k4.z, k4.w};
            int cc[4] = {c4.x, c4.y, c4.z, c4.w};
            float vv[4] = {v4.x, v4.y, v4.z, v4.w};
            #pragma unroll
            for (int u = 0; u < 4; ++u) {
                int r = r4 * 4 + u;
                int key = n + kk[u];
                px[r] = cc[u] | ((key & (BKEYS - 1)) << 17);
                pv[r] = __float_as_int(vv[u] * theta[cc[u]]);
                pb[r] = (short)(key >> BUCKET_BITS);
                atomicAdd(&hist4[wv][pb[r]], 1);
            }
        }
        nvalid = RPT;
    } else if (rbeg >= 2 * nnz && rbeg + RPT <= 3 * nnz) {
        int e0 = rbeg - 2 * nnz;
        #pragma unroll
        for (int r4 = 0; r4 < RPT / 4; ++r4) {
            int4 k4 = *reinterpret_cast<const int4*>(&idxC[e0 + r4 * 4]);
            int4 c4 = *reinterpret_cast<const int4*>(&idxC[nnz + e0 + r4 * 4]);
            float4 v4 = *reinterpret_cast<const float4*>(&valC[e0 + r4 * 4]);
            int kk[4] = {k4.x, k4.y, k4.z, k4.w};
            int cc[4] = {c4.x, c4.y, c4.z, c4.w};
            float vv[4] = {v4.x, v4.y, v4.z, v4.w};
            #pragma unroll
            for (int u = 0; u < 4; ++u) {
                int r = r4 * 4 + u;
                int key = 2 * n + kk[u];
                px[r] = cc[u] | ((key & (BKEYS - 1)) << 17);
                pv[r] = __float_as_int(vv[u]);
                pb[r] = (short)(key >> BUCKET_BITS);
                atomicAdd(&hist4[wv][pb[r]], 1);
            }
        }
        nvalid = RPT;
    } else {
        #pragma unroll
        for (int r = 0; r < RPT; ++r) {
            int i = rbeg + r;
            if (i >= end) break;
            int key, c;
            float v;
            if (i < nnz) {
                key = idxA[i];
                c = idxA[nnz + i];
                v = valA[i];
            } else if (i < 2 * nnz) {
                int e = i - nnz;
                key = n + idxB[e];
                c = idxB[nnz + e];
                v = valB[e] * theta[c];
            } else {
                int e = i - 2 * nnz;
                key = 2 * n + idxC[e];
                c = idxC[nnz + e];
                v = valC[e];
            }
            px[r] = c | ((key & (BKEYS - 1)) << 17);
            pv[r] = __float_as_int(v);
            pb[r] = (short)(key >> BUCKET_BITS);
            atomicAdd(&hist4[wv][pb[r]], 1);
            ++nvalid;
        }
    }
    __syncthreads();

    // combine per-wave hists; inclusive scan over 512 slots (2/thread)
    int h0 = hist4[0][t] + hist4[1][t] + hist4[2][t] + hist4[3][t];
    int h1 = hist4[0][t + 256] + hist4[1][t + 256] + hist4[2][t + 256] + hist4[3][t + 256];
    sc[t] = h0; sc[t + 256] = h1;
    __syncthreads();
    for (int off = 1; off < NBMAX; off <<= 1) {
        int a = (t >= off) ? sc[t - off] : 0;
        int b2 = (t + 256 >= off) ? sc[t + 256 - off] : 0;
        __syncthreads();
        sc[t] += a; sc[t + 256] += b2;
        __syncthreads();
    }
    // per-wave cursor sub-ranges (exclusive prefix over waves within bucket)
    {
        int st0 = sc[t] - h0;
        int st1 = sc[t + 256] - h1;
        int a0 = st0, a1 = st1;
        wcur[0][t] = a0;              a0 += hist4[0][t];
        wcur[1][t] = a0;              a0 += hist4[1][t];
        wcur[2][t] = a0;              a0 += hist4[2][t];
        wcur[3][t] = a0;
        wcur[0][t + 256] = a1;        a1 += hist4[0][t + 256];
        wcur[1][t + 256] = a1;        a1 += hist4[1][t + 256];
        wcur[2][t + 256] = a1;        a1 += hist4[2][t + 256];
        wcur[3][t + 256] = a1;
    }
    __syncthreads();

    // metadata: contiguous chunk-major write (local exclusive starts + sentinel)
    for (int b = t; b <= nb; b += 256)
        locA[(size_t)blockIdx.x * (nb + 1) + b] = (b < nb) ? wcur[0][b] : csize;

    // phase 3: scatter from registers; each wave bumps only ITS cursors
    #pragma unroll
    for (int r = 0; r < RPT; ++r) {
        if (r < nvalid) {
            int pos = atomicAdd(&wcur[wv][pb[r]], 1);
            recsTmp[(size_t)base + pos] = make_int2(px[r], pv[r]);
        }
    }
}

// ---------- bucket totals ----------
__global__ __launch_bounds__(256) void bucket_totals(const int* __restrict__ locA,
                                                     int nchA, int nb,
                                                     int* __restrict__ tot) {
    __shared__ int red[256];
    int b = blockIdx.x;
    int t = threadIdx.x;
    int s = 0;
    for (int ch = t; ch < nchA; ch += 256) {
        const int* lc = &locA[(size_t)ch * (nb + 1)];
        s += lc[b + 1] - lc[b];
    }
    red[t] = s;
    __syncthreads();
    for (int off = 128; off > 0; off >>= 1) {
        if (t < off) red[t] += red[t + off];
        __syncthreads();
    }
    if (t == 0) tot[b] = red[0];
}

__global__ void scan_sums_kernel(int* __restrict__ chunk_sums, int nchunks) {
    __shared__ int tmp[SUMS_BLOCK];
    __shared__ int carry_s;
    int tid = threadIdx.x;
    if (tid == 0) carry_s = 0;
    __syncthreads();
    for (int base = 0; base < nchunks; base += SUMS_BLOCK) {
        int i = base + tid;
        int v = (i < nchunks) ? chunk_sums[i] : 0;
        tmp[tid] = v;
        __syncthreads();
        for (int off = 1; off < SUMS_BLOCK; off <<= 1) {
            int y = (tid >= off) ? tmp[tid - off] : 0;
            __syncthreads();
            tmp[tid] += y;
            __syncthreads();
        }
        int c = carry_s;
        if (i < nchunks) chunk_sums[i] = tmp[tid] - v + c;   // exclusive
        int total = tmp[SUMS_BLOCK - 1];
        __syncthreads();
        if (tid == 0) carry_s = c + total;
        __syncthreads();
    }
}

// ---------- pass B (R16 version): key-sort into LDS out-buffer, flush -----
// rec = (c << 15) | (bf16(v) & 0x7FFF)  -- all values positive.
__global__ __launch_bounds__(1024) void passB_kernel(const int2* __restrict__ recsTmp,
                                                     const int* __restrict__ locA,
                                                     const int* __restrict__ bsArr,
                                                     int nchA, int nb, int n3,
                                                     int* __restrict__ start_g,
                                                     int* __restrict__ counts_g,
                                                     unsigned* __restrict__ recs) {
    __shared__ int hist[BKEYS];          // 4 KB
    __shared__ int scan[BKEYS];          // 4 KB
    __shared__ unsigned outb[STAG_CAP];  // 72 KB
    int b = blockIdx.x;
    int t = threadIdx.x;
    int wave = t >> 6, lane = t & 63;
    int grp = lane >> 4, gl = lane & 15;
    int bs = bsArr[b];
    hist[t] = 0;
    __syncthreads();

    for (int ch = wave * 4 + grp; ch < nchA; ch += 64) {
        const int* lc = &locA[(size_t)ch * (nb + 1)];
        int ls = lc[b], le = lc[b + 1];
        size_t cb = (size_t)ch * CHUNK_E;
        for (int k = ls + gl; k < le; k += 16)
            atomicAdd(&hist[(recsTmp[cb + k].x >> 17) & (BKEYS - 1)], 1);
    }
    __syncthreads();

    int v = hist[t];
    scan[t] = v;
    __syncthreads();
    for (int off = 1; off < BKEYS; off <<= 1) {
        int y = (t >= off) ? scan[t - off] : 0;
        __syncthreads();
        scan[t] += y;
        __syncthreads();
    }
    int excl = scan[t] - v;
    int key = (b << BUCKET_BITS) + t;
    if (key < n3) {
        start_g[key] = bs + excl;
        counts_g[key] = v;
    }
    int totalB = scan[BKEYS - 1];
    hist[t] = excl;                      // reuse as cursor
    __syncthreads();

    if (totalB <= STAG_CAP) {
        for (int ch = wave * 4 + grp; ch < nchA; ch += 64) {
            const int* lc = &locA[(size_t)ch * (nb + 1)];
            int ls = lc[b], le = lc[b + 1];
            size_t cb = (size_t)ch * CHUNK_E;
            for (int k = ls + gl; k < le; k += 16) {
                int2 r = recsTmp[cb + k];
                int kk = (r.x >> 17) & (BKEYS - 1);
                int pos = atomicAdd(&hist[kk], 1);
                unsigned c = (unsigned)(r.x & 0x1FFFF);
                unsigned bv = (unsigned)f2bf(__int_as_float(r.y)) & 0x7FFFu;
                outb[pos] = (c << 15) | bv;
            }
        }
        __syncthreads();
        for (int k = t; k < totalB; k += 1024)
            recs[(size_t)bs + k] = outb[k];
    } else {
        for (int ch = wave * 4 + grp; ch < nchA; ch += 64) {
            const int* lc = &locA[(size_t)ch * (nb + 1)];
            int ls = lc[b], le = lc[b + 1];
            size_t cb = (size_t)ch * CHUNK_E;
            for (int k = ls + gl; k < le; k += 16) {
                int2 r = recsTmp[cb + k];
                int kk = (r.x >> 17) & (BKEYS - 1);
                int pos = atomicAdd(&hist[kk], 1);
                unsigned c = (unsigned)(r.x & 0x1FFFF);
                unsigned bv = (unsigned)f2bf(__int_as_float(r.y)) & 0x7FFFu;
                recs[(size_t)bs + pos] = (c << 15) | bv;
            }
        }
    }
}

// ---------- Pull SpMM (R16 version): 32 lanes/row, shfl broadcast ---------
__global__ __launch_bounds__(256) void pull_spmm_bf16(
        const unsigned* __restrict__ recs,
        const int* __restrict__ start,
        const int* __restrict__ counts,
        const ushort* __restrict__ dense,   // bf16 rows of 128
        ushort* __restrict__ outb,          // bf16 out (or null)
        float* __restrict__ outf,           // f32 out (or null)
        int n, int do_relu) {
    int grp32 = threadIdx.x >> 5;           // 8 row-groups per block
    int lane = threadIdx.x & 31;
    int row = blockIdx.x * 8 + grp32;
    if (row >= n) return;
    int s = start[row];
    int cnt = counts[row];
    const ushort4* dp = reinterpret_cast<const ushort4*>(dense);  // 32 per row
    float a0 = 0.0f, a1 = 0.0f, a2 = 0.0f, a3 = 0.0f;

    for (int jb = 0; jb < cnt; jb += 32) {
        int nbatch = min(32, cnt - jb);
        unsigned myrec = (lane < nbatch) ? recs[s + jb + lane] : 0u;
        int j = 0;
        for (; j + 4 <= nbatch; j += 4) {
            unsigned r0 = __shfl(myrec, j + 0, 32);
            unsigned r1 = __shfl(myrec, j + 1, 32);
            unsigned r2 = __shfl(myrec, j + 2, 32);
            unsigned r3 = __shfl(myrec, j + 3, 32);
            ushort4 d0 = dp[(size_t)(r0 >> 15) * 32 + lane];
            ushort4 d1 = dp[(size_t)(r1 >> 15) * 32 + lane];
            ushort4 d2 = dp[(size_t)(r2 >> 15) * 32 + lane];
            ushort4 d3 = dp[(size_t)(r3 >> 15) * 32 + lane];
            float v0 = __uint_as_float((r0 & 0x7FFFu) << 16);
            float v1 = __uint_as_float((r1 & 0x7FFFu) << 16);
            float v2 = __uint_as_float((r2 & 0x7FFFu) << 16);
            float v3 = __uint_as_float((r3 & 0x7FFFu) << 16);
            a0 = fmaf(v0, bf2f(d0.x), a0); a1 = fmaf(v0, bf2f(d0.y), a1);
            a2 = fmaf(v0, bf2f(d0.z), a2); a3 = fmaf(v0, bf2f(d0.w), a3);
            a0 = fmaf(v1, bf2f(d1.x), a0); a1 = fmaf(v1, bf2f(d1.y), a1);
            a2 = fmaf(v1, bf2f(d1.z), a2); a3 = fmaf(v1, bf2f(d1.w), a3);
            a0 = fmaf(v2, bf2f(d2.x), a0); a1 = fmaf(v2, bf2f(d2.y), a1);
            a2 = fmaf(v2, bf2f(d2.z), a2); a3 = fmaf(v2, bf2f(d2.w), a3);
            a0 = fmaf(v3, bf2f(d3.x), a0); a1 = fmaf(v3, bf2f(d3.y), a1);
            a2 = fmaf(v3, bf2f(d3.z), a2); a3 = fmaf(v3, bf2f(d3.w), a3);
        }
        for (; j < nbatch; ++j) {
            unsigned r0 = __shfl(myrec, j, 32);
            ushort4 d0 = dp[(size_t)(r0 >> 15) * 32 + lane];
            float v0 = __uint_as_float((r0 & 0x7FFFu) << 16);
            a0 = fmaf(v0, bf2f(d0.x), a0); a1 = fmaf(v0, bf2f(d0.y), a1);
            a2 = fmaf(v0, bf2f(d0.z), a2); a3 = fmaf(v0, bf2f(d0.w), a3);
        }
    }
    if (do_relu) {
        a0 = fmaxf(a0, 0.0f); a1 = fmaxf(a1, 0.0f);
        a2 = fmaxf(a2, 0.0f); a3 = fmaxf(a3, 0.0f);
    }
    if (outb) {
        ushort4 o = {f2bf(a0), f2bf(a1), f2bf(a2), f2bf(a3)};
        reinterpret_cast<ushort4*>(outb)[(size_t)row * 32 + lane] = o;
    } else {
        float4 o = {a0, a1, a2, a3};
        *reinterpret_cast<float4*>(&outf[(size_t)row * CH + lane * 4]) = o;
    }
}

// ---------- host-side orchestration ----------

extern "C" void kernel_launch(void* const* d_in, const int* in_sizes, int n_in,
                              void* d_out, int out_size, void* d_ws, size_t ws_size,
                              hipStream_t stream) {
    const int*   phi_idx  = (const int*)d_in[0];
    const float* phi_val  = (const float*)d_in[1];
    const int*   phii_idx = (const int*)d_in[2];
    const float* phii_val = (const float*)d_in[3];
    const int*   f_idx    = (const int*)d_in[4];
    const float* f_val    = (const float*)d_in[5];
    const float* W        = (const float*)d_in[6];
    const float* theta    = (const float*)d_in[7];

    const int nnz = in_sizes[1];            // 1,600,000
    const int n   = in_sizes[7];            // 100,000
    const int n3  = 3 * n;                  // triple key space
    const int total = 3 * nnz;              // 4.8M records

    const int nb   = (n3 + BKEYS - 1) >> BUCKET_BITS;               // 293 (<=511)
    const int nchA = (total + CHUNK_E - 1) / CHUNK_E;               // 1172

    float* out = (float*)d_out;

    // workspace (~75 MB). The 51.2 MB "dense region" holds recsTmp (38.4 MB)
    // during the build; after passB it is reused as filtered_bf16 [0,25.6)
    // and z_bf16 [25.6,51.2).
    char* ws = (char*)d_ws;
    char*  dense_region = ws;
    int2*  recsTmp  = (int2*)dense_region;                 // 38.4 MB (build only)
    ushort* filt_b  = (ushort*)dense_region;               // 25.6 MB
    ushort* z_b     = (ushort*)(dense_region + (size_t)n * CH * sizeof(ushort));
    ws += (size_t)n * CH * sizeof(float);                  // 51.2 MB region
    unsigned* recs  = (unsigned*)ws;        ws += (size_t)total * sizeof(unsigned);
    int* counts     = (int*)ws;             ws += (size_t)n3 * sizeof(int);
    int* start      = (int*)ws;             ws += (size_t)n3 * sizeof(int);
    int* locA       = (int*)ws;             ws += (size_t)nchA * (nb + 1) * sizeof(int);
    int* tot        = (int*)ws;             ws += 4096;
    ushort* w_b     = (ushort*)ws;          ws += CH * CH * sizeof(ushort);

    const int row_blocks = (n + 7) / 8;     // 8 rows per 256-thread block

    // --- W -> bf16 (independent; overlaps build) ---
    conv_w_kernel<<<(CH * CH + 255) / 256, 256, 0, stream>>>(W, w_b);

    // --- radix CSR build: all three sparse matrices in one key space ---
    passA_sort<<<nchA, 256, 0, stream>>>(phii_idx, phii_val, phi_idx, phi_val,
                                         f_idx, f_val, theta,
                                         nnz, n, nb, locA, recsTmp);
    bucket_totals<<<nb, 256, 0, stream>>>(locA, nchA, nb, tot);
    scan_sums_kernel<<<1, SUMS_BLOCK, 0, stream>>>(tot, nb);
    passB_kernel<<<nb, 1024, 0, stream>>>(recsTmp, locA, tot, nchA, nb, n3,
                                          start, counts, recs);

    // 1) filtered = F @ W       (keys [2n,3n); W bf16 L1-resident; bf16 out)
    pull_spmm_bf16<<<row_blocks, 256, 0, stream>>>(
        recs, start + 2 * n, counts + 2 * n, w_b, filt_b, nullptr, n, 0);

    // 2) z = Phi_inv @ filtered (keys [0,n); bf16 in/out)
    pull_spmm_bf16<<<row_blocks, 256, 0, stream>>>(
        recs, start, counts, filt_b, z_b, nullptr, n, 0);

    // 3) out = relu(Phi @ (theta .* z))  (keys [n,2n); theta pre-folded; f32 out)
    pull_spmm_bf16<<<row_blocks, 256, 0, stream>>>(
        recs, start + n, counts + n, z_b, nullptr, out, n, 1);
}

// Round 20
// 236.521 us; speedup vs baseline: 1.2631x; 1.0754x over previous
//
#include <hip/hip_runtime.h>

#define CH 128          // C_IN == C_OUT == 128
#define SUMS_BLOCK 512
#define CHUNK_E 4096    // records per chunk = private recsTmp window
#define RPT 16          // records per thread in passA (CHUNK_E / 256)
#define BUCKET_BITS 10  // 1024 keys per bucket
#define BKEYS (1 << BUCKET_BITS)
#define NBMAX 512       // max buckets (LDS arrays padded to this)
#define STAG_CAP 18432  // passB LDS out-buffer capacity

__device__ inline ushort f2bf(float f) {          // RNE f32 -> bf16
    unsigned b = __float_as_uint(f);
    return (ushort)((b + 0x7FFF + ((b >> 16) & 1)) >> 16);
}
__device__ inline float bf2f(ushort u) {
    return __uint_as_float((unsigned)u << 16);
}

// ---------- W -> bf16 conversion ----------
__global__ void conv_w_kernel(const float* __restrict__ W,
                              ushort* __restrict__ Wb) {
    int i = blockIdx.x * blockDim.x + threadIdx.x;
    if (i < CH * CH) Wb[i] = f2bf(W[i]);
}

// ---------- pass A v3: single-read, register-held chunk sort --------------
// Triple key space: Phi_inv i -> idxA[i]; Phi -> n+idxB[e]; F -> 2n+idxC[e].
// recsTmp record (8 B): x = c | (key&1023)<<17  (c < 2^17), y = f32 val bits.
__global__ __launch_bounds__(256) void passA_sort(const int* __restrict__ idxA,
                                                  const float* __restrict__ valA,
                                                  const int* __restrict__ idxB,
                                                  const float* __restrict__ valB,
                                                  const int* __restrict__ idxC,
                                                  const float* __restrict__ valC,
                                                  const float* __restrict__ theta,
                                                  int nnz, int n, int nb,
                                                  int* __restrict__ locA,
                                                  int2* __restrict__ recsTmp) {
    __shared__ int hist[NBMAX];
    __shared__ int sc[NBMAX];
    __shared__ int cur[NBMAX];
    int t = threadIdx.x;
    hist[t] = 0; hist[t + 256] = 0;
    __syncthreads();

    int base = blockIdx.x * CHUNK_E;
    int end = min(base + CHUNK_E, 3 * nnz);
    int csize = end - base;
    int rbeg = base + t * RPT;

    int px[RPT];    // packed x (c | keylow<<17)
    int pv[RPT];    // value bits (f32)
    short pb[RPT];  // bucket id

    int nvalid = 0;
    if (rbeg + RPT <= nnz) {
        #pragma unroll
        for (int r4 = 0; r4 < RPT / 4; ++r4) {
            int4 k4 = *reinterpret_cast<const int4*>(&idxA[rbeg + r4 * 4]);
            int4 c4 = *reinterpret_cast<const int4*>(&idxA[nnz + rbeg + r4 * 4]);
            float4 v4 = *reinterpret_cast<const float4*>(&valA[rbeg + r4 * 4]);
            int kk[4] = {k4.x, k4.y, k4.z, k4.w};
            int cc[4] = {c4.x, c4.y, c4.z, c4.w};
            float vv[4] = {v4.x, v4.y, v4.z, v4.w};
            #pragma unroll
            for (int u = 0; u < 4; ++u) {
                int r = r4 * 4 + u;
                px[r] = cc[u] | ((kk[u] & (BKEYS - 1)) << 17);
                pv[r] = __float_as_int(vv[u]);
                pb[r] = (short)(kk[u] >> BUCKET_BITS);
                atomicAdd(&hist[pb[r]], 1);
            }
        }
        nvalid = RPT;
    } else if (rbeg >= nnz && rbeg + RPT <= 2 * nnz) {
        int e0 = rbeg - nnz;
        #pragma unroll
        for (int r4 = 0; r4 < RPT / 4; ++r4) {
            int4 k4 = *reinterpret_cast<const int4*>(&idxB[e0 + r4 * 4]);
            int4 c4 = *reinterpret_cast<const int4*>(&idxB[nnz + e0 + r4 * 4]);
            float4 v4 = *reinterpret_cast<const float4*>(&valB[e0 + r4 * 4]);
            int kk[4] = {k4.x, k4.y, k4.z, k4.w};
            int cc[4] = {c4.x, c4.y, c4.z, c4.w};
            float vv[4] = {v4.x, v4.y, v4.z, v4.w};
            #pragma unroll
            for (int u = 0; u < 4; ++u) {
                int r = r4 * 4 + u;
                int key = n + kk[u];
                px[r] = cc[u] | ((key & (BKEYS - 1)) << 17);
                pv[r] = __float_as_int(vv[u] * theta[cc[u]]);
                pb[r] = (short)(key >> BUCKET_BITS);
                atomicAdd(&hist[pb[r]], 1);
            }
        }
        nvalid = RPT;
    } else if (rbeg >= 2 * nnz && rbeg + RPT <= 3 * nnz) {
        int e0 = rbeg - 2 * nnz;
        #pragma unroll
        for (int r4 = 0; r4 < RPT / 4; ++r4) {
            int4 k4 = *reinterpret_cast<const int4*>(&idxC[e0 + r4 * 4]);
            int4 c4 = *reinterpret_cast<const int4*>(&idxC[nnz + e0 + r4 * 4]);
            float4 v4 = *reinterpret_cast<const float4*>(&valC[e0 + r4 * 4]);
            int kk[4] = {k4.x, k4.y, k4.z, k4.w};
            int cc[4] = {c4.x, c4.y, c4.z, c4.w};
            float vv[4] = {v4.x, v4.y, v4.z, v4.w};
            #pragma unroll
            for (int u = 0; u < 4; ++u) {
                int r = r4 * 4 + u;
                int key = 2 * n + kk[u];
                px[r] = cc[u] | ((key & (BKEYS - 1)) << 17);
                pv[r] = __float_as_int(vv[u]);
                pb[r] = (short)(key >> BUCKET_BITS);
                atomicAdd(&hist[pb[r]], 1);
            }
        }
        nvalid = RPT;
    } else {
        #pragma unroll
        for (int r = 0; r < RPT; ++r) {
            int i = rbeg + r;
            if (i >= end) break;
            int key, c;
            float v;
            if (i < nnz) {
                key = idxA[i];
                c = idxA[nnz + i];
                v = valA[i];
            } else if (i < 2 * nnz) {
                int e = i - nnz;
                key = n + idxB[e];
                c = idxB[nnz + e];
                v = valB[e] * theta[c];
            } else {
                int e = i - 2 * nnz;
                key = 2 * n + idxC[e];
                c = idxC[nnz + e];
                v = valC[e];
            }
            px[r] = c | ((key & (BKEYS - 1)) << 17);
            pv[r] = __float_as_int(v);
            pb[r] = (short)(key >> BUCKET_BITS);
            atomicAdd(&hist[pb[r]], 1);
            ++nvalid;
        }
    }
    __syncthreads();

    sc[t] = hist[t]; sc[t + 256] = hist[t + 256];
    __syncthreads();
    for (int off = 1; off < NBMAX; off <<= 1) {
        int a = (t >= off) ? sc[t - off] : 0;
        int b2 = (t + 256 >= off) ? sc[t + 256 - off] : 0;
        __syncthreads();
        sc[t] += a; sc[t + 256] += b2;
        __syncthreads();
    }
    cur[t] = sc[t] - hist[t];
    cur[t + 256] = sc[t + 256] - hist[t + 256];
    __syncthreads();

    for (int b = t; b <= nb; b += 256)
        locA[(size_t)blockIdx.x * (nb + 1) + b] = (b < nb) ? (sc[b] - hist[b]) : csize;

    #pragma unroll
    for (int r = 0; r < RPT; ++r) {
        if (r < nvalid) {
            int pos = atomicAdd(&cur[pb[r]], 1);
            recsTmp[(size_t)base + pos] = make_int2(px[r], pv[r]);
        }
    }
}

// ---------- bucket totals ----------
__global__ __launch_bounds__(256) void bucket_totals(const int* __restrict__ locA,
                                                     int nchA, int nb,
                                                     int* __restrict__ tot) {
    __shared__ int red[256];
    int b = blockIdx.x;
    int t = threadIdx.x;
    int s = 0;
    for (int ch = t; ch < nchA; ch += 256) {
        const int* lc = &locA[(size_t)ch * (nb + 1)];
        s += lc[b + 1] - lc[b];
    }
    red[t] = s;
    __syncthreads();
    for (int off = 128; off > 0; off >>= 1) {
        if (t < off) red[t] += red[t + off];
        __syncthreads();
    }
    if (t == 0) tot[b] = red[0];
}

__global__ void scan_sums_kernel(int* __restrict__ chunk_sums, int nchunks) {
    __shared__ int tmp[SUMS_BLOCK];
    __shared__ int carry_s;
    int tid = threadIdx.x;
    if (tid == 0) carry_s = 0;
    __syncthreads();
    for (int base = 0; base < nchunks; base += SUMS_BLOCK) {
        int i = base + tid;
        int v = (i < nchunks) ? chunk_sums[i] : 0;
        tmp[tid] = v;
        __syncthreads();
        for (int off = 1; off < SUMS_BLOCK; off <<= 1) {
            int y = (tid >= off) ? tmp[tid - off] : 0;
            __syncthreads();
            tmp[tid] += y;
            __syncthreads();
        }
        int c = carry_s;
        if (i < nchunks) chunk_sums[i] = tmp[tid] - v + c;   // exclusive
        int total = tmp[SUMS_BLOCK - 1];
        __syncthreads();
        if (tid == 0) carry_s = c + total;
        __syncthreads();
    }
}

// ---------- pass B: key-sort into LDS out-buffer, linear flush ------------
// rec = (c << 15) | (bf16(v) & 0x7FFF)  -- all values positive.
__global__ __launch_bounds__(1024) void passB_kernel(const int2* __restrict__ recsTmp,
                                                     const int* __restrict__ locA,
                                                     const int* __restrict__ bsArr,
                                                     int nchA, int nb, int n3,
                                                     int* __restrict__ start_g,
                                                     int* __restrict__ counts_g,
                                                     unsigned* __restrict__ recs) {
    __shared__ int hist[BKEYS];          // 4 KB
    __shared__ int scan[BKEYS];          // 4 KB
    __shared__ unsigned outb[STAG_CAP];  // 72 KB
    int b = blockIdx.x;
    int t = threadIdx.x;
    int wave = t >> 6, lane = t & 63;
    int grp = lane >> 4, gl = lane & 15;
    int bs = bsArr[b];
    hist[t] = 0;
    __syncthreads();

    for (int ch = wave * 4 + grp; ch < nchA; ch += 64) {
        const int* lc = &locA[(size_t)ch * (nb + 1)];
        int ls = lc[b], le = lc[b + 1];
        size_t cb = (size_t)ch * CHUNK_E;
        for (int k = ls + gl; k < le; k += 16)
            atomicAdd(&hist[(recsTmp[cb + k].x >> 17) & (BKEYS - 1)], 1);
    }
    __syncthreads();

    int v = hist[t];
    scan[t] = v;
    __syncthreads();
    for (int off = 1; off < BKEYS; off <<= 1) {
        int y = (t >= off) ? scan[t - off] : 0;
        __syncthreads();
        scan[t] += y;
        __syncthreads();
    }
    int excl = scan[t] - v;
    int key = (b << BUCKET_BITS) + t;
    if (key < n3) {
        start_g[key] = bs + excl;
        counts_g[key] = v;
    }
    int totalB = scan[BKEYS - 1];
    hist[t] = excl;                      // reuse as cursor
    __syncthreads();

    if (totalB <= STAG_CAP) {
        for (int ch = wave * 4 + grp; ch < nchA; ch += 64) {
            const int* lc = &locA[(size_t)ch * (nb + 1)];
            int ls = lc[b], le = lc[b + 1];
            size_t cb = (size_t)ch * CHUNK_E;
            for (int k = ls + gl; k < le; k += 16) {
                int2 r = recsTmp[cb + k];
                int kk = (r.x >> 17) & (BKEYS - 1);
                int pos = atomicAdd(&hist[kk], 1);
                unsigned c = (unsigned)(r.x & 0x1FFFF);
                unsigned bv = (unsigned)f2bf(__int_as_float(r.y)) & 0x7FFFu;
                outb[pos] = (c << 15) | bv;
            }
        }
        __syncthreads();
        for (int k = t; k < totalB; k += 1024)
            recs[(size_t)bs + k] = outb[k];
    } else {
        for (int ch = wave * 4 + grp; ch < nchA; ch += 64) {
            const int* lc = &locA[(size_t)ch * (nb + 1)];
            int ls = lc[b], le = lc[b + 1];
            size_t cb = (size_t)ch * CHUNK_E;
            for (int k = ls + gl; k < le; k += 16) {
                int2 r = recsTmp[cb + k];
                int kk = (r.x >> 17) & (BKEYS - 1);
                int pos = atomicAdd(&hist[kk], 1);
                unsigned c = (unsigned)(r.x & 0x1FFFF);
                unsigned bv = (unsigned)f2bf(__int_as_float(r.y)) & 0x7FFFu;
                recs[(size_t)bs + pos] = (c << 15) | bv;
            }
        }
    }
}

// ---------- Pull SpMM: 32 lanes/row, cooperative rec prefetch + shfl ------
__global__ __launch_bounds__(256) void pull_spmm_bf16(
        const unsigned* __restrict__ recs,
        const int* __restrict__ start,
        const int* __restrict__ counts,
        const ushort* __restrict__ dense,   // bf16 rows of 128
        ushort* __restrict__ outb,          // bf16 out (or null)
        float* __restrict__ outf,           // f32 out (or null)
        int n, int do_relu) {
    int grp32 = threadIdx.x >> 5;           // 8 row-groups per block
    int lane = threadIdx.x & 31;
    int row = blockIdx.x * 8 + grp32;
    if (row >= n) return;
    int s = start[row];
    int cnt = counts[row];
    const ushort4* dp = reinterpret_cast<const ushort4*>(dense);  // 32 per row
    float a0 = 0.0f, a1 = 0.0f, a2 = 0.0f, a3 = 0.0f;

    for (int jb = 0; jb < cnt; jb += 32) {
        int nbatch = min(32, cnt - jb);
        unsigned myrec = (lane < nbatch) ? recs[s + jb + lane] : 0u;
        int j = 0;
        for (; j + 4 <= nbatch; j += 4) {
            unsigned r0 = __shfl(myrec, j + 0, 32);
            unsigned r1 = __shfl(myrec, j + 1, 32);
            unsigned r2 = __shfl(myrec, j + 2, 32);
            unsigned r3 = __shfl(myrec, j + 3, 32);
            ushort4 d0 = dp[(size_t)(r0 >> 15) * 32 + lane];
            ushort4 d1 = dp[(size_t)(r1 >> 15) * 32 + lane];
            ushort4 d2 = dp[(size_t)(r2 >> 15) * 32 + lane];
            ushort4 d3 = dp[(size_t)(r3 >> 15) * 32 + lane];
            float v0 = __uint_as_float((r0 & 0x7FFFu) << 16);
            float v1 = __uint_as_float((r1 & 0x7FFFu) << 16);
            float v2 = __uint_as_float((r2 & 0x7FFFu) << 16);
            float v3 = __uint_as_float((r3 & 0x7FFFu) << 16);
            a0 = fmaf(v0, bf2f(d0.x), a0); a1 = fmaf(v0, bf2f(d0.y), a1);
            a2 = fmaf(v0, bf2f(d0.z), a2); a3 = fmaf(v0, bf2f(d0.w), a3);
            a0 = fmaf(v1, bf2f(d1.x), a0); a1 = fmaf(v1, bf2f(d1.y), a1);
            a2 = fmaf(v1, bf2f(d1.z), a2); a3 = fmaf(v1, bf2f(d1.w), a3);
            a0 = fmaf(v2, bf2f(d2.x), a0); a1 = fmaf(v2, bf2f(d2.y), a1);
            a2 = fmaf(v2, bf2f(d2.z), a2); a3 = fmaf(v2, bf2f(d2.w), a3);
            a0 = fmaf(v3, bf2f(d3.x), a0); a1 = fmaf(v3, bf2f(d3.y), a1);
            a2 = fmaf(v3, bf2f(d3.z), a2); a3 = fmaf(v3, bf2f(d3.w), a3);
        }
        for (; j < nbatch; ++j) {
            unsigned r0 = __shfl(myrec, j, 32);
            ushort4 d0 = dp[(size_t)(r0 >> 15) * 32 + lane];
            float v0 = __uint_as_float((r0 & 0x7FFFu) << 16);
            a0 = fmaf(v0, bf2f(d0.x), a0); a1 = fmaf(v0, bf2f(d0.y), a1);
            a2 = fmaf(v0, bf2f(d0.z), a2); a3 = fmaf(v0, bf2f(d0.w), a3);
        }
    }
    if (do_relu) {
        a0 = fmaxf(a0, 0.0f); a1 = fmaxf(a1, 0.0f);
        a2 = fmaxf(a2, 0.0f); a3 = fmaxf(a3, 0.0f);
    }
    if (outb) {
        ushort4 o = {f2bf(a0), f2bf(a1), f2bf(a2), f2bf(a3)};
        reinterpret_cast<ushort4*>(outb)[(size_t)row * 32 + lane] = o;
    } else {
        float4 o = {a0, a1, a2, a3};
        *reinterpret_cast<float4*>(&outf[(size_t)row * CH + lane * 4]) = o;
    }
}

// ---------- host-side orchestration ----------

extern "C" void kernel_launch(void* const* d_in, const int* in_sizes, int n_in,
                              void* d_out, int out_size, void* d_ws, size_t ws_size,
                              hipStream_t stream) {
    const int*   phi_idx  = (const int*)d_in[0];
    const float* phi_val  = (const float*)d_in[1];
    const int*   phii_idx = (const int*)d_in[2];
    const float* phii_val = (const float*)d_in[3];
    const int*   f_idx    = (const int*)d_in[4];
    const float* f_val    = (const float*)d_in[5];
    const float* W        = (const float*)d_in[6];
    const float* theta    = (const float*)d_in[7];

    const int nnz = in_sizes[1];            // 1,600,000
    const int n   = in_sizes[7];            // 100,000
    const int n3  = 3 * n;                  // triple key space
    const int total = 3 * nnz;              // 4.8M records

    const int nb   = (n3 + BKEYS - 1) >> BUCKET_BITS;               // 293 (<=511)
    const int nchA = (total + CHUNK_E - 1) / CHUNK_E;               // 1172

    float* out = (float*)d_out;

    // workspace (~75 MB). The 51.2 MB "dense region" holds recsTmp (38.4 MB)
    // during the build; after passB it is reused as filtered_bf16 [0,25.6)
    // and z_bf16 [25.6,51.2).
    char* ws = (char*)d_ws;
    char*  dense_region = ws;
    int2*  recsTmp  = (int2*)dense_region;                 // 38.4 MB (build only)
    ushort* filt_b  = (ushort*)dense_region;               // 25.6 MB
    ushort* z_b     = (ushort*)(dense_region + (size_t)n * CH * sizeof(ushort));
    ws += (size_t)n * CH * sizeof(float);                  // 51.2 MB region
    unsigned* recs  = (unsigned*)ws;        ws += (size_t)total * sizeof(unsigned);
    int* counts     = (int*)ws;             ws += (size_t)n3 * sizeof(int);
    int* start      = (int*)ws;             ws += (size_t)n3 * sizeof(int);
    int* locA       = (int*)ws;             ws += (size_t)nchA * (nb + 1) * sizeof(int);
    int* tot        = (int*)ws;             ws += 4096;
    ushort* w_b     = (ushort*)ws;          ws += CH * CH * sizeof(ushort);

    const int row_blocks = (n + 7) / 8;     // 8 rows per 256-thread block

    // --- W -> bf16 (independent; overlaps build) ---
    conv_w_kernel<<<(CH * CH + 255) / 256, 256, 0, stream>>>(W, w_b);

    // --- radix CSR build: all three sparse matrices in one key space ---
    passA_sort<<<nchA, 256, 0, stream>>>(phii_idx, phii_val, phi_idx, phi_val,
                                         f_idx, f_val, theta,
                                         nnz, n, nb, locA, recsTmp);
    bucket_totals<<<nb, 256, 0, stream>>>(locA, nchA, nb, tot);
    scan_sums_kernel<<<1, SUMS_BLOCK, 0, stream>>>(tot, nb);
    passB_kernel<<<nb, 1024, 0, stream>>>(recsTmp, locA, tot, nchA, nb, n3,
                                          start, counts, recs);

    // 1) filtered = F @ W       (keys [2n,3n); W bf16 L1-resident; bf16 out)
    pull_spmm_bf16<<<row_blocks, 256, 0, stream>>>(
        recs, start + 2 * n, counts + 2 * n, w_b, filt_b, nullptr, n, 0);

    // 2) z = Phi_inv @ filtered (keys [0,n); bf16 in/out)
    pull_spmm_bf16<<<row_blocks, 256, 0, stream>>>(
        recs, start, counts, filt_b, z_b, nullptr, n, 0);

    // 3) out = relu(Phi @ (theta .* z))  (keys [n,2n); theta pre-folded; f32 out)
    pull_spmm_bf16<<<row_blocks, 256, 0, stream>>>(
        recs, start + n, counts + n, z_b, nullptr, out, n, 1);
}